// Round 6
// baseline (385.970 us; speedup 1.0000x reference)
//
#include <hip/hip_runtime.h>
#include <hip/hip_bf16.h>

#define NN 50000
#define EE 800000
#define ETOT 850000   // EE + NN self-loops
#define FIN 500
#define HC 128        // 8 heads * 16 ch
#define NH 8
#define CH 16
#define NC 7

// canonical fp32 weight-buffer offsets
#define OW1  0
#define OAS1 64000
#define OAD1 64128
#define OB1  64256
#define OW2  64384
#define OAS2 65280
#define OAD2 65287
#define OB2  65294
#define WTOT 65301

#define KPAD 512
#define GEMM1_BLOCKS 512
#define ESTR 133

typedef __hip_bfloat16 bf16;
typedef __attribute__((ext_vector_type(8))) short short8;
typedef __attribute__((ext_vector_type(4))) float f32x4;

__device__ __forceinline__ float b2f(const bf16 v) { return __bfloat162float(v); }
__device__ __forceinline__ float lrelu(float v) { return fmaxf(v, 0.2f * v); }
__device__ __forceinline__ float elog(float v) { return __expf(fminf(lrelu(v), 30.f)); }
__device__ __forceinline__ float blo(unsigned w) { return __uint_as_float(w << 16); }
__device__ __forceinline__ float bhi(unsigned w) { return __uint_as_float(w & 0xffff0000u); }
__device__ __forceinline__ unsigned short f2bu(float f)
{
    bf16 h = __float2bfloat16(f);
    return *(unsigned short*)&h;
}
__device__ __forceinline__ unsigned pk2(float a, float b)
{
    return (unsigned)f2bu(a) | ((unsigned)f2bu(b) << 16);
}

// low-word read: int64 indices are < 2^31, little-endian -> low dword suffices
__device__ __forceinline__ int eread(const void* __restrict__ eidx, long long i, int is64)
{
    if (is64) return ((const int*)eidx)[2 * i];
    return ((const int*)eidx)[i];
}

// ---------------- dtype detection + rowptr sentinel ----------------
__global__ void detect_kernel(const unsigned short* __restrict__ xraw,
                              const unsigned int* __restrict__ eraw,
                              int* __restrict__ flags, int* __restrict__ rowptr)
{
    __shared__ int s_insane, s_oddnz;
    if (threadIdx.x == 0) { s_insane = 0; s_oddnz = 0; }
    __syncthreads();
    int insane = 0;
    for (int i = threadIdx.x; i < 8192; i += 256) {
        const unsigned int bits = ((unsigned int)xraw[i]) << 16;
        const float v = __uint_as_float(bits);
        const float a = fabsf(v);
        const bool sane = (v == 0.0f) || (a >= 1e-30f && a <= 1e4f);
        if (!sane) insane++;
    }
    int oddnz = 0;
    for (int i = threadIdx.x; i < 512; i += 256) {
        if (eraw[2 * i + 1] != 0u) oddnz++;
    }
    atomicAdd(&s_insane, insane);
    atomicAdd(&s_oddnz, oddnz);
    __syncthreads();
    if (threadIdx.x == 0) {
        flags[0] = (s_insane < 256) ? 1 : 0;
        flags[1] = (s_oddnz == 0) ? 1 : 0;
        rowptr[NN] = ETOT;   // sentinel: rowptr holds immutable starts + end
    }
}

// ---------------- canonicalize weights to fp32 + build w1t (merged) ----------------
__global__ void conv_all_kernel(const void* W1, const void* as1, const void* ad1, const void* b1,
                                const void* W2, const void* as2, const void* ad2, const void* b2,
                                float* __restrict__ wc, unsigned short* __restrict__ w1t,
                                const int* __restrict__ flags)
{
    const int i = blockIdx.x * blockDim.x + threadIdx.x;
    const int isbf = flags[0];
    if (i < WTOT) {
        const void* src; int off;
        if (i < OAS1)      { src = W1;  off = i - OW1; }
        else if (i < OAD1) { src = as1; off = i - OAS1; }
        else if (i < OB1)  { src = ad1; off = i - OAD1; }
        else if (i < OW2)  { src = b1;  off = i - OB1; }
        else if (i < OAS2) { src = W2;  off = i - OW2; }
        else if (i < OAD2) { src = as2; off = i - OAS2; }
        else if (i < OB2)  { src = ad2; off = i - OAD2; }
        else               { src = b2;  off = i - OB2; }
        float v;
        if (isbf) v = b2f(((const bf16*)src)[off]);
        else      v = ((const float*)src)[off];
        wc[i] = v;
    }
    if (i < HC * KPAD) {
        const int col = i >> 9;
        const int k   = i & (KPAD - 1);
        float v = 0.f;
        if (k < FIN) {
            if (isbf) v = b2f(((const bf16*)W1)[k * HC + col]);
            else      v = ((const float*)W1)[k * HC + col];
        }
        w1t[i] = f2bu(v);
    }
}

// ---------------- CSR build: histogram of dst ----------------
__global__ void hist_kernel(const void* __restrict__ eidx, int* __restrict__ deg,
                            const int* __restrict__ flags)
{
    const int e = blockIdx.x * blockDim.x + threadIdx.x;
    if (e >= ETOT) return;
    int d;
    if (e < EE) d = eread(eidx, (long long)EE + e, flags[1]);
    else        d = e - EE;
    if ((unsigned)d < (unsigned)NN) atomicAdd(&deg[d], 1);
}

// ---------------- scan k1 ----------------
__global__ void scan_k1_kernel(const int* __restrict__ deg, int* __restrict__ bsum)
{
    __shared__ int lds[256];
    const int i = blockIdx.x * 256 + threadIdx.x;
    lds[threadIdx.x] = (i < NN) ? deg[i] : 0;
    __syncthreads();
    for (int s = 128; s > 0; s >>= 1) {
        if (threadIdx.x < s) lds[threadIdx.x] += lds[threadIdx.x + s];
        __syncthreads();
    }
    if (threadIdx.x == 0) bsum[blockIdx.x] = lds[0];
}

// ---------------- scan k2 ----------------
__global__ void scan_k2_kernel(int* __restrict__ bsum)
{
    __shared__ int a[256], b[256], orig[256];
    const int t = threadIdx.x;
    a[t] = bsum[t]; orig[t] = a[t];
    __syncthreads();
    int* cur = a; int* nxt = b;
    for (int off = 1; off < 256; off <<= 1) {
        nxt[t] = cur[t] + ((t >= off) ? cur[t - off] : 0);
        __syncthreads();
        int* tmp = cur; cur = nxt; nxt = tmp;
    }
    bsum[t] = cur[t] - orig[t];
}

// ---------------- scan k3: rowptr[i] = exclusive start of node i ----------------
__global__ void scan_k3_kernel(const int* __restrict__ deg, const int* __restrict__ bsum,
                               int* __restrict__ rowptr)
{
    __shared__ int a[256], b[256], own[256];
    const int t = threadIdx.x;
    const int i = blockIdx.x * 256 + t;
    const int v = (i < NN) ? deg[i] : 0;
    a[t] = v; own[t] = v;
    __syncthreads();
    int* cur = a; int* nxt = b;
    for (int off = 1; off < 256; off <<= 1) {
        nxt[t] = cur[t] + ((t >= off) ? cur[t - off] : 0);
        __syncthreads();
        int* tmp = cur; cur = nxt; nxt = tmp;
    }
    if (i < NN) rowptr[i] = bsum[blockIdx.x] + cur[t] - own[t];
}

// ---------------- CSR scatter: pos = rowptr[d] + atomic cursor ----------------
__global__ void scatter_kernel(const void* __restrict__ eidx, const int* __restrict__ rowptr,
                               int* __restrict__ cur, int* __restrict__ esrc_sorted,
                               const int* __restrict__ flags)
{
    const int e = blockIdx.x * blockDim.x + threadIdx.x;
    if (e >= ETOT) return;
    int s, d;
    if (e < EE) {
        s = eread(eidx, e, flags[1]);
        d = eread(eidx, (long long)EE + e, flags[1]);
    } else s = d = e - EE;
    if ((unsigned)s >= (unsigned)NN || (unsigned)d >= (unsigned)NN) return;
    const int pos = rowptr[d] + atomicAdd(&cur[d], 1);
    if ((unsigned)pos < (unsigned)ETOT) esrc_sorted[pos] = s;
}

// ---------------- GEMM1 v6: v5 compute + coalesced reshape epilogue ----------
// 512 blocks x 8 waves; wave wv holds full-K B fragments for head wv in 64
// VGPRs. Block streams 16-row chunks of x through a swizzled LDS dbuf (T14
// reg-staging). NEW vs v5: per-chunk epilogue writes acc into a dedicated
// Esl[16][133] f32 tile, then 256 threads emit h1 as contiguous uint4 stores
// and 128 threads emit att1 dots with fully coalesced a_src1/a_dst1 stores —
// eliminating the partial-sector RMW traffic that tripled v5's HBM bytes.
__global__ __launch_bounds__(512, 4) void gemm1_mfma_kernel(
    const void* __restrict__ x, const unsigned short* __restrict__ w1t,
    bf16* __restrict__ h1, const float* __restrict__ wc,
    float* __restrict__ a_src1, float* __restrict__ a_dst1,
    const int* __restrict__ flags)
{
    __shared__ __align__(16) unsigned char Asm[2][16384];
    __shared__ float Esl[16][ESTR];
    __shared__ float attw[256];

    const int t    = threadIdx.x;      // 0..511
    const int wv   = t >> 6;
    const int lane = t & 63;
    const int m15  = lane & 15;
    const int quad = lane >> 4;
    const int bid  = blockIdx.x;
    const int isbf = flags[0];
    const unsigned char* xB = (const unsigned char*)x;

    // contiguous chunk range: 3125 = 512*6 + 53
    const int nc = 6 + (bid < 53 ? 1 : 0);
    const int c0 = bid * 6 + (bid < 53 ? bid : 53);

    if (t < 256) attw[t] = wc[OAS1 + t];   // as1[128] | ad1[128] contiguous

    // B preload: full K for col (wv*16 + m15), 16 x short8 = 64 VGPRs
    const unsigned short* bp = w1t + (size_t)(wv * 16 + m15) * KPAD + quad * 8;
    short8 Breg[16];
#pragma unroll
    for (int kt = 0; kt < 16; ++kt)
        Breg[kt] = *(const short8*)(bp + kt * 32);

    // zero-pad k in [500,512) of every row, both buffers (staging never writes
    // off >= 1000, so this persists across chunks)
    if (t < 96) {
        const int buf = t / 48, idx = t % 48;
        const int row = idx / 3, p = idx % 3;
        const int off = 1000 + p * 8;
        *(unsigned long long*)(&Asm[buf][row * 1024 +
            ((off & ~15) ^ ((row & 7) << 4)) + (off & 8)]) = 0ull;
    }

    // swizzled ds_write of an 8B unit at (row, byte off in [0,1000), off%8==0)
    auto swaddr = [&](unsigned char* lb, int row, int off) -> unsigned long long* {
        return (unsigned long long*)(lb + row * 1024 +
            ((off & ~15) ^ ((row & 7) << 4)) + (off & 8));
    };

    // synchronous stage of chunk c -> buf (prologue only)
    auto stage_sync = [&](int c, int buf) {
        unsigned char* lb = &Asm[buf][0];
        if (isbf) {
            const unsigned char* base = xB + (size_t)c * 16000;
#pragma unroll
            for (int j = 0; j < 4; ++j) {
                const int u = t + 512 * j;
                if (u < 2000) {
                    const unsigned long long v = *(const unsigned long long*)(base + u * 8);
                    const int row = u / 125;
                    const int off = (u - row * 125) * 8;
                    *swaddr(lb, row, off) = v;
                }
            }
        } else {
            const unsigned char* base = xB + (size_t)c * 32000;
#pragma unroll
            for (int j = 0; j < 4; ++j) {
                const int u = t + 512 * j;
                if (u < 2000) {
                    const float4 v = *(const float4*)(base + u * 16);
                    const unsigned long long w = (unsigned long long)pk2(v.x, v.y)
                                               | ((unsigned long long)pk2(v.z, v.w) << 32);
                    const int b = u * 16;
                    const int row = b / 2000;
                    const int off = (b - row * 2000) >> 1;
                    *swaddr(lb, row, off) = w;
                }
            }
        }
    };

    stage_sync(c0, 0);
    __syncthreads();

    for (int ci = 0; ci < nc; ++ci) {
        const int cr0 = (c0 + ci) * 16;
        const unsigned char* Ab = &Asm[ci & 1][0];
        const bool pre = (ci + 1 < nc);

        // ---- T14 issue-early: next chunk's global loads into registers ----
        unsigned long long gb[4];
        float4 gf[4];
        if (pre) {
            if (isbf) {
                const unsigned char* base = xB + (size_t)(c0 + ci + 1) * 16000;
#pragma unroll
                for (int j = 0; j < 4; ++j) {
                    const int u = t + 512 * j;
                    gb[j] = (u < 2000) ? *(const unsigned long long*)(base + u * 8) : 0ull;
                }
            } else {
                const unsigned char* base = xB + (size_t)(c0 + ci + 1) * 32000;
#pragma unroll
                for (int j = 0; j < 4; ++j) {
                    const int u = t + 512 * j;
                    gf[j] = (u < 2000) ? *(const float4*)(base + u * 16)
                                       : make_float4(0.f, 0.f, 0.f, 0.f);
                }
            }
        }

        // ---- compute: 16 chained MFMAs from swizzled LDS + resident B ----
        f32x4 acc = (f32x4){0.f, 0.f, 0.f, 0.f};
#pragma unroll
        for (int kt = 0; kt < 16; ++kt) {
            const int g = kt * 4 + quad;
            const short8 a = *(const short8*)(Ab + m15 * 1024 +
                                              ((g * 16) ^ ((m15 & 7) << 4)));
            acc = __builtin_amdgcn_mfma_f32_16x16x32_bf16(a, Breg[kt], acc, 0, 0, 0);
        }

        // ---- acc -> Esl reshape tile ----
#pragma unroll
        for (int reg = 0; reg < 4; ++reg)
            Esl[quad * 4 + reg][wv * 16 + m15] = acc[reg];
        __syncthreads();   // Esl complete (also: Asm[ci&1] fully consumed)

        // ---- coalesced stores from Esl ----
        if (t < 256) {
            // h1: thread t -> row t>>4, 8 cols starting at (t&15)*8 -> uint4
            const int row = t >> 4;
            const int sg  = t & 15;
            const float* ep = &Esl[row][sg * 8];
            uint4 w0;
            w0.x = pk2(ep[0], ep[1]); w0.y = pk2(ep[2], ep[3]);
            w0.z = pk2(ep[4], ep[5]); w0.w = pk2(ep[6], ep[7]);
            *(uint4*)(h1 + (size_t)(cr0 + row) * HC + sg * 8) = w0;
        } else if (t < 384) {
            // att1: thread u -> (row u>>3, head u&7); writes are contiguous
            const int u   = t - 256;
            const int row = u >> 3;
            const int hh  = u & 7;
            const float* rp = &Esl[row][hh * 16];
            float s = 0.f, d = 0.f;
#pragma unroll
            for (int c = 0; c < 16; ++c) {
                s += rp[c] * attw[hh * 16 + c];
                d += rp[c] * attw[128 + hh * 16 + c];
            }
            a_src1[(size_t)(cr0 + row) * NH + hh] = s;
            a_dst1[(size_t)(cr0 + row) * NH + hh] = d;
        }

        // ---- T14 write-late: commit staged regs to the other buffer ----
        if (pre) {
            unsigned char* lb = &Asm[(ci + 1) & 1][0];
            if (isbf) {
#pragma unroll
                for (int j = 0; j < 4; ++j) {
                    const int u = t + 512 * j;
                    if (u < 2000) {
                        const int row = u / 125;
                        const int off = (u - row * 125) * 8;
                        *swaddr(lb, row, off) = gb[j];
                    }
                }
            } else {
#pragma unroll
                for (int j = 0; j < 4; ++j) {
                    const int u = t + 512 * j;
                    if (u < 2000) {
                        const unsigned long long w = (unsigned long long)pk2(gf[j].x, gf[j].y)
                                                   | ((unsigned long long)pk2(gf[j].z, gf[j].w) << 32);
                        const int b = u * 16;
                        const int row = b / 2000;
                        const int off = (b - row * 2000) >> 1;
                        *swaddr(lb, row, off) = w;
                    }
                }
            }
        }
        __syncthreads();   // next A-buffer ready; Esl reads done
    }
}

// ---------------- layer-1 fused gather + fused GEMM2/bias/relu + fused att2 ----------------
__global__ __launch_bounds__(256) void gather1_kernel(
    const int* __restrict__ rowptr, const int* __restrict__ esrc_sorted,
    const float* __restrict__ a_src, const float* __restrict__ a_dst,
    const bf16* __restrict__ h1, const float* __restrict__ wc,
    float* __restrict__ h2, float* __restrict__ a_src2, float* __restrict__ a_dst2)
{
    __shared__ float W2s[HC * NC];
    __shared__ float B1s[HC];
    for (int i = threadIdx.x; i < HC * NC; i += 256) W2s[i] = wc[OW2 + i];
    if (threadIdx.x < HC) B1s[threadIdx.x] = wc[OB1 + threadIdx.x];
    __syncthreads();

    const int node = blockIdx.x * 4 + (threadIdx.x >> 6);
    if (node >= NN) return;
    const int lane = threadIdx.x & 63;
    const int h = lane >> 3;
    const float ad = a_dst[node * NH + h];
    const int start = rowptr[node];
    const int end   = rowptr[node + 1];
    float acc0 = 0.f, acc1 = 0.f, den = 0.f;
    int i = start;
    for (; i + 8 <= end; i += 8) {
        int   sv[8];
        float ev[8];
        unsigned wv[8];
#pragma unroll
        for (int j = 0; j < 8; ++j) sv[j] = esrc_sorted[i + j];
#pragma unroll
        for (int j = 0; j < 8; ++j) ev[j] = a_src[sv[j] * NH + h];
#pragma unroll
        for (int j = 0; j < 8; ++j) wv[j] = *(const unsigned*)(h1 + (size_t)sv[j] * HC + 2 * lane);
#pragma unroll
        for (int j = 0; j < 8; ++j) {
            const float n = elog(ev[j] + ad);
            acc0 += n * blo(wv[j]);
            acc1 += n * bhi(wv[j]);
            den  += n;
        }
    }
    for (; i < end; ++i) {
        const int s = esrc_sorted[i];
        const float num = elog(a_src[s * NH + h] + ad);
        const unsigned w = *(const unsigned*)(h1 + (size_t)s * HC + 2 * lane);
        acc0 += num * blo(w);
        acc1 += num * bhi(w);
        den  += num;
    }
    const float inv = 1.f / (den + 1e-16f);

    // fused GEMM2: this wave holds the whole out1 row (2 channels / lane).
    const int k0 = 2 * lane;
    const float r0v = fmaxf(acc0 * inv + B1s[k0],     0.f);
    const float r1v = fmaxf(acc1 * inv + B1s[k0 + 1], 0.f);
    float p[NC];
#pragma unroll
    for (int c = 0; c < NC; ++c)
        p[c] = r0v * W2s[k0 * NC + c] + r1v * W2s[(k0 + 1) * NC + c];
    // 64-lane butterfly reduce (7 channels)
#pragma unroll
    for (int m = 1; m < 64; m <<= 1) {
#pragma unroll
        for (int c = 0; c < NC; ++c) p[c] += __shfl_xor(p[c], m);
    }
    if (lane == 0) {
        float ps = 0.f, pd = 0.f;
        float* hp = h2 + (size_t)node * NC;
#pragma unroll
        for (int c = 0; c < NC; ++c) {
            hp[c] = p[c];
            ps += p[c] * wc[OAS2 + c];
            pd += p[c] * wc[OAD2 + c];
        }
        a_src2[node] = ps;
        a_dst2[node] = pd;
    }
}

// ---------------- layer-2 fused gather ----------------
__global__ void gather2_kernel(
    const int* __restrict__ rowptr, const int* __restrict__ esrc_sorted,
    const float* __restrict__ a_src, const float* __restrict__ a_dst,
    const float* __restrict__ h2, const float* __restrict__ wc,
    void* __restrict__ out, const int* __restrict__ flags)
{
    const int node = blockIdx.x * 32 + (threadIdx.x >> 3);
    if (node >= NN) return;
    const int c = threadIdx.x & 7;
    const float ad = a_dst[node];
    const int start = rowptr[node];
    const int end   = rowptr[node + 1];
    const int cc = (c < NC) ? c : 0;
    float acc = 0.f, den = 0.f;
    int i = start;
    for (; i + 4 <= end; i += 4) {
        const int s0 = esrc_sorted[i + 0];
        const int s1 = esrc_sorted[i + 1];
        const int s2 = esrc_sorted[i + 2];
        const int s3 = esrc_sorted[i + 3];
        const float e0 = a_src[s0];
        const float e1 = a_src[s1];
        const float e2 = a_src[s2];
        const float e3 = a_src[s3];
        const float v0 = h2[s0 * NC + cc];
        const float v1 = h2[s1 * NC + cc];
        const float v2 = h2[s2 * NC + cc];
        const float v3 = h2[s3 * NC + cc];
        const float n0 = elog(e0 + ad);
        const float n1 = elog(e1 + ad);
        const float n2 = elog(e2 + ad);
        const float n3 = elog(e3 + ad);
        acc += n0 * v0 + n1 * v1 + n2 * v2 + n3 * v3;
        den += n0 + n1 + n2 + n3;
    }
    for (; i < end; ++i) {
        const int s = esrc_sorted[i];
        const float num = elog(a_src[s] + ad);
        den += num;
        acc += num * h2[s * NC + cc];
    }
    if (c >= NC) return;
    const float v = acc / (den + 1e-16f) + wc[OB2 + c];
    if (flags[0]) ((bf16*)out)[node * NC + c] = __float2bfloat16(v);
    else          ((float*)out)[node * NC + c] = v;
}

extern "C" void kernel_launch(void* const* d_in, const int* in_sizes, int n_in,
                              void* d_out, int out_size, void* d_ws, size_t ws_size,
                              hipStream_t stream)
{
    const void* x        = d_in[0];
    const void* eidx     = d_in[1];
    const void* W1       = d_in[2];
    const void* att_src1 = d_in[3];
    const void* att_dst1 = d_in[4];
    const void* b1       = d_in[5];
    const void* W2       = d_in[6];
    const void* att_src2 = d_in[7];
    const void* att_dst2 = d_in[8];
    const void* b2       = d_in[9];

    float* ws = (float*)d_ws;
    size_t o = 0;
    int*   flags  = (int*)(ws + o);            o += 16;
    float* wc     = ws + o;                    o += 65312;
    unsigned short* w1t = (unsigned short*)(ws + o); o += (HC * KPAD) / 2;
    int*   deg    = (int*)(ws + o);            o += 50000;
    int*   cur    = (int*)(ws + o);            o += 50000;   // contiguous with deg for one memset
    int*   rowptr = (int*)(ws + o);            o += 50016;
    int*   bsum   = (int*)(ws + o);            o += 256;
    int*   esrt   = (int*)(ws + o);            o += 850000;
    bf16*  h1     = (bf16*)(ws + o);           o += (size_t)NN * HC / 2;
    float* a_src1 = ws + o;                    o += (size_t)NN * NH;
    float* a_dst1 = ws + o;                    o += (size_t)NN * NH;
    float* h2     = ws + o;                    o += (size_t)NN * NC;
    float* a_src2 = ws + o;                    o += NN;
    float* a_dst2 = ws + o;                    o += NN;

    detect_kernel<<<1, 256, 0, stream>>>((const unsigned short*)x, (const unsigned int*)eidx,
                                         flags, rowptr);
    conv_all_kernel<<<(HC * KPAD + 255) / 256, 256, 0, stream>>>(
        W1, att_src1, att_dst1, b1, W2, att_src2, att_dst2, b2, wc, w1t, flags);
    hipMemsetAsync(deg, 0, 2 * (size_t)NN * sizeof(int), stream);
    hist_kernel<<<(ETOT + 255) / 256, 256, 0, stream>>>(eidx, deg, flags);
    scan_k1_kernel<<<(NN + 255) / 256, 256, 0, stream>>>(deg, bsum);
    scan_k2_kernel<<<1, 256, 0, stream>>>(bsum);
    scan_k3_kernel<<<(NN + 255) / 256, 256, 0, stream>>>(deg, bsum, rowptr);
    scatter_kernel<<<(ETOT + 255) / 256, 256, 0, stream>>>(eidx, rowptr, cur, esrt, flags);

    gemm1_mfma_kernel<<<GEMM1_BLOCKS, 512, 0, stream>>>(x, w1t, h1, wc,
                                                        a_src1, a_dst1, flags);
    gather1_kernel<<<(NN + 3) / 4, 256, 0, stream>>>(rowptr, esrt, a_src1, a_dst1, h1, wc,
                                                     h2, a_src2, a_dst2);
    gather2_kernel<<<(NN + 31) / 32, 256, 0, stream>>>(rowptr, esrt, a_src2, a_dst2, h2, wc,
                                                       d_out, flags);
}

// Round 7
// 364.395 us; speedup vs baseline: 1.0592x; 1.0592x over previous
//
#include <hip/hip_runtime.h>
#include <hip/hip_bf16.h>

#define NN 50000
#define EE 800000
#define ETOT 850000   // EE + NN self-loops
#define FIN 500
#define HC 128        // 8 heads * 16 ch
#define NH 8
#define CH 16
#define NC 7

// canonical fp32 weight-buffer offsets
#define OW1  0
#define OAS1 64000
#define OAD1 64128
#define OB1  64256
#define OW2  64384
#define OAS2 65280
#define OAD2 65287
#define OB2  65294
#define WTOT 65301

// MFMA gemm1 tiling (round-0 structure)
#define GR1  64
#define GK   32
#define KPAD 512
#define ASTR 40
#define BSTR 40

typedef __hip_bfloat16 bf16;
typedef __attribute__((ext_vector_type(8))) short short8;
typedef __attribute__((ext_vector_type(4))) float f32x4;

__device__ __forceinline__ float b2f(const bf16 v) { return __bfloat162float(v); }
__device__ __forceinline__ float lrelu(float v) { return fmaxf(v, 0.2f * v); }
__device__ __forceinline__ float elog(float v) { return __expf(fminf(lrelu(v), 30.f)); }
__device__ __forceinline__ float blo(unsigned w) { return __uint_as_float(w << 16); }
__device__ __forceinline__ float bhi(unsigned w) { return __uint_as_float(w & 0xffff0000u); }
__device__ __forceinline__ unsigned short f2bu(float f)
{
    bf16 h = __float2bfloat16(f);
    return *(unsigned short*)&h;
}

// low-word read: int64 indices are < 2^31, little-endian -> low dword suffices
__device__ __forceinline__ int eread(const void* __restrict__ eidx, long long i, int is64)
{
    if (is64) return ((const int*)eidx)[2 * i];
    return ((const int*)eidx)[i];
}

// ---------------- dtype detection + rowptr sentinel ----------------
__global__ void detect_kernel(const unsigned short* __restrict__ xraw,
                              const unsigned int* __restrict__ eraw,
                              int* __restrict__ flags, int* __restrict__ rowptr)
{
    __shared__ int s_insane, s_oddnz;
    if (threadIdx.x == 0) { s_insane = 0; s_oddnz = 0; }
    __syncthreads();
    int insane = 0;
    for (int i = threadIdx.x; i < 8192; i += 256) {
        const unsigned int bits = ((unsigned int)xraw[i]) << 16;
        const float v = __uint_as_float(bits);
        const float a = fabsf(v);
        const bool sane = (v == 0.0f) || (a >= 1e-30f && a <= 1e4f);
        if (!sane) insane++;
    }
    int oddnz = 0;
    for (int i = threadIdx.x; i < 512; i += 256) {
        if (eraw[2 * i + 1] != 0u) oddnz++;
    }
    atomicAdd(&s_insane, insane);
    atomicAdd(&s_oddnz, oddnz);
    __syncthreads();
    if (threadIdx.x == 0) {
        flags[0] = (s_insane < 256) ? 1 : 0;
        flags[1] = (s_oddnz == 0) ? 1 : 0;
        rowptr[NN] = ETOT;   // sentinel: rowptr holds immutable starts + end
    }
}

// ---------------- canonicalize weights to fp32 + build w1t (merged) ----------------
__global__ void conv_all_kernel(const void* W1, const void* as1, const void* ad1, const void* b1,
                                const void* W2, const void* as2, const void* ad2, const void* b2,
                                float* __restrict__ wc, unsigned short* __restrict__ w1t,
                                const int* __restrict__ flags)
{
    const int i = blockIdx.x * blockDim.x + threadIdx.x;
    const int isbf = flags[0];
    if (i < WTOT) {
        const void* src; int off;
        if (i < OAS1)      { src = W1;  off = i - OW1; }
        else if (i < OAD1) { src = as1; off = i - OAS1; }
        else if (i < OB1)  { src = ad1; off = i - OAD1; }
        else if (i < OW2)  { src = b1;  off = i - OB1; }
        else if (i < OAS2) { src = W2;  off = i - OW2; }
        else if (i < OAD2) { src = as2; off = i - OAS2; }
        else if (i < OB2)  { src = ad2; off = i - OAD2; }
        else               { src = b2;  off = i - OB2; }
        float v;
        if (isbf) v = b2f(((const bf16*)src)[off]);
        else      v = ((const float*)src)[off];
        wc[i] = v;
    }
    if (i < HC * KPAD) {
        const int col = i >> 9;
        const int k   = i & (KPAD - 1);
        float v = 0.f;
        if (k < FIN) {
            if (isbf) v = b2f(((const bf16*)W1)[k * HC + col]);
            else      v = ((const float*)W1)[k * HC + col];
        }
        w1t[i] = f2bu(v);
    }
}

// ---------------- CSR build: histogram of dst ----------------
__global__ void hist_kernel(const void* __restrict__ eidx, int* __restrict__ deg,
                            const int* __restrict__ flags)
{
    const int e = blockIdx.x * blockDim.x + threadIdx.x;
    if (e >= ETOT) return;
    int d;
    if (e < EE) d = eread(eidx, (long long)EE + e, flags[1]);
    else        d = e - EE;
    if ((unsigned)d < (unsigned)NN) atomicAdd(&deg[d], 1);
}

// ---------------- scan k1 ----------------
__global__ void scan_k1_kernel(const int* __restrict__ deg, int* __restrict__ bsum)
{
    __shared__ int lds[256];
    const int i = blockIdx.x * 256 + threadIdx.x;
    lds[threadIdx.x] = (i < NN) ? deg[i] : 0;
    __syncthreads();
    for (int s = 128; s > 0; s >>= 1) {
        if (threadIdx.x < s) lds[threadIdx.x] += lds[threadIdx.x + s];
        __syncthreads();
    }
    if (threadIdx.x == 0) bsum[blockIdx.x] = lds[0];
}

// ---------------- scan k2 ----------------
__global__ void scan_k2_kernel(int* __restrict__ bsum)
{
    __shared__ int a[256], b[256], orig[256];
    const int t = threadIdx.x;
    a[t] = bsum[t]; orig[t] = a[t];
    __syncthreads();
    int* cur = a; int* nxt = b;
    for (int off = 1; off < 256; off <<= 1) {
        nxt[t] = cur[t] + ((t >= off) ? cur[t - off] : 0);
        __syncthreads();
        int* tmp = cur; cur = nxt; nxt = tmp;
    }
    bsum[t] = cur[t] - orig[t];
}

// ---------------- scan k3: rowptr[i] = exclusive start of node i ----------------
__global__ void scan_k3_kernel(const int* __restrict__ deg, const int* __restrict__ bsum,
                               int* __restrict__ rowptr)
{
    __shared__ int a[256], b[256], own[256];
    const int t = threadIdx.x;
    const int i = blockIdx.x * 256 + t;
    const int v = (i < NN) ? deg[i] : 0;
    a[t] = v; own[t] = v;
    __syncthreads();
    int* cur = a; int* nxt = b;
    for (int off = 1; off < 256; off <<= 1) {
        nxt[t] = cur[t] + ((t >= off) ? cur[t - off] : 0);
        __syncthreads();
        int* tmp = cur; cur = nxt; nxt = tmp;
    }
    if (i < NN) rowptr[i] = bsum[blockIdx.x] + cur[t] - own[t];
}

// ---------------- CSR scatter: pos = rowptr[d] + atomic cursor ----------------
__global__ void scatter_kernel(const void* __restrict__ eidx, const int* __restrict__ rowptr,
                               int* __restrict__ cur, int* __restrict__ esrc_sorted,
                               const int* __restrict__ flags)
{
    const int e = blockIdx.x * blockDim.x + threadIdx.x;
    if (e >= ETOT) return;
    int s, d;
    if (e < EE) {
        s = eread(eidx, e, flags[1]);
        d = eread(eidx, (long long)EE + e, flags[1]);
    } else s = d = e - EE;
    if ((unsigned)s >= (unsigned)NN || (unsigned)d >= (unsigned)NN) return;
    const int pos = rowptr[d] + atomicAdd(&cur[d], 1);
    if ((unsigned)pos < (unsigned)ETOT) esrc_sorted[pos] = s;
}

// ---------------- GEMM1 (MFMA bf16) — round-0 structure, plain epilogue ----------------
__global__ __launch_bounds__(256) void gemm1_mfma_kernel(
    const void* __restrict__ x, const unsigned short* __restrict__ w1t,
    bf16* __restrict__ h1, const int* __restrict__ flags)
{
    __shared__ unsigned short Asl[GR1 * ASTR];
    __shared__ unsigned short Bsl[HC * BSTR];

    const int t    = threadIdx.x;
    const int wv   = t >> 6;
    const int lane = t & 63;
    const int m15  = lane & 15;
    const int quad = lane >> 4;
    const int r0   = blockIdx.x * GR1;
    const int isbf = flags[0];
    const float* xf = (const float*)x;
    const bf16*  xb = (const bf16*)x;

    const int wr  = (wv >> 1) * 32;
    const int wcb = (wv & 1) * 64;

    f32x4 acc[2][4];
#pragma unroll
    for (int i = 0; i < 2; ++i)
#pragma unroll
        for (int j = 0; j < 4; ++j) acc[i][j] = (f32x4){0.f, 0.f, 0.f, 0.f};

    const int arow = t >> 2;
    const int akk  = (t & 3) * 8;
    const int bcol = t & 127;
    const int bks  = (t >> 7) * 16;

    for (int kt = 0; kt < 16; ++kt) {
        const int k0 = kt * GK;
        {
            const int grow = r0 + arow;
            if (!isbf && grow < NN && (k0 + akk + 8) <= FIN) {
                const size_t base = (size_t)grow * FIN + k0 + akk;
                const float4 v0 = *(const float4*)(xf + base);
                const float4 v1 = *(const float4*)(xf + base + 4);
                uint4 pk;
                pk.x = (unsigned)f2bu(v0.x) | ((unsigned)f2bu(v0.y) << 16);
                pk.y = (unsigned)f2bu(v0.z) | ((unsigned)f2bu(v0.w) << 16);
                pk.z = (unsigned)f2bu(v1.x) | ((unsigned)f2bu(v1.y) << 16);
                pk.w = (unsigned)f2bu(v1.z) | ((unsigned)f2bu(v1.w) << 16);
                *(uint4*)&Asl[arow * ASTR + akk] = pk;
            } else {
#pragma unroll
                for (int j = 0; j < 8; ++j) {
                    const int k = k0 + akk + j;
                    float v = 0.f;
                    if (grow < NN && k < FIN)
                        v = isbf ? b2f(xb[(size_t)grow * FIN + k]) : xf[(size_t)grow * FIN + k];
                    Asl[arow * ASTR + akk + j] = f2bu(v);
                }
            }
        }
        {
            const unsigned short* gp = w1t + (size_t)bcol * KPAD + k0 + bks;
            *(uint4*)&Bsl[bcol * BSTR + bks]     = *(const uint4*)gp;
            *(uint4*)&Bsl[bcol * BSTR + bks + 8] = *(const uint4*)(gp + 8);
        }
        __syncthreads();

        const int ak = quad * 8;
        const short8 a0 = *(const short8*)&Asl[(wr + m15) * ASTR + ak];
        const short8 a1 = *(const short8*)&Asl[(wr + 16 + m15) * ASTR + ak];
#pragma unroll
        for (int ct = 0; ct < 4; ++ct) {
            const short8 b = *(const short8*)&Bsl[(wcb + ct * 16 + m15) * BSTR + ak];
            acc[0][ct] = __builtin_amdgcn_mfma_f32_16x16x32_bf16(a0, b, acc[0][ct], 0, 0, 0);
            acc[1][ct] = __builtin_amdgcn_mfma_f32_16x16x32_bf16(a1, b, acc[1][ct], 0, 0, 0);
        }
        __syncthreads();
    }

#pragma unroll
    for (int rt = 0; rt < 2; ++rt) {
#pragma unroll
        for (int reg = 0; reg < 4; ++reg) {
            const int row = r0 + wr + rt * 16 + quad * 4 + reg;
            if (row < NN) {
                bf16* hp = h1 + (size_t)row * HC;
#pragma unroll
                for (int ct = 0; ct < 4; ++ct)
                    hp[wcb + ct * 16 + m15] = __float2bfloat16(acc[rt][ct][reg]);
            }
        }
    }
}

// ---------------- per-node attention logits, layer 1 (round-0) ----------------
__global__ void att1_kernel(const bf16* __restrict__ h1, const float* __restrict__ wc,
                            float* __restrict__ a_src, float* __restrict__ a_dst)
{
    const int idx = blockIdx.x * blockDim.x + threadIdx.x;
    if (idx >= NN * NH) return;
    const int h = idx & 7;
    const unsigned int* hp = (const unsigned int*)(h1 + (size_t)(idx >> 3) * HC + h * CH);
    float s = 0.f, d = 0.f;
#pragma unroll
    for (int u = 0; u < 8; ++u) {
        const unsigned int w = hp[u];
        s += blo(w) * wc[OAS1 + h * CH + 2 * u] + bhi(w) * wc[OAS1 + h * CH + 2 * u + 1];
        d += blo(w) * wc[OAD1 + h * CH + 2 * u] + bhi(w) * wc[OAD1 + h * CH + 2 * u + 1];
    }
    a_src[idx] = s;
    a_dst[idx] = d;
}

// ---------------- layer-1 fused gather + fused GEMM2/bias/relu + fused att2 ----------------
__global__ __launch_bounds__(256) void gather1_kernel(
    const int* __restrict__ rowptr, const int* __restrict__ esrc_sorted,
    const float* __restrict__ a_src, const float* __restrict__ a_dst,
    const bf16* __restrict__ h1, const float* __restrict__ wc,
    float* __restrict__ h2, float* __restrict__ a_src2, float* __restrict__ a_dst2)
{
    __shared__ float W2s[HC * NC];
    __shared__ float B1s[HC];
    for (int i = threadIdx.x; i < HC * NC; i += 256) W2s[i] = wc[OW2 + i];
    if (threadIdx.x < HC) B1s[threadIdx.x] = wc[OB1 + threadIdx.x];
    __syncthreads();

    const int node = blockIdx.x * 4 + (threadIdx.x >> 6);
    if (node >= NN) return;
    const int lane = threadIdx.x & 63;
    const int h = lane >> 3;
    const float ad = a_dst[node * NH + h];
    const int start = rowptr[node];
    const int end   = rowptr[node + 1];
    float acc0 = 0.f, acc1 = 0.f, den = 0.f;
    int i = start;
    for (; i + 8 <= end; i += 8) {
        int   sv[8];
        float ev[8];
        unsigned wv[8];
#pragma unroll
        for (int j = 0; j < 8; ++j) sv[j] = esrc_sorted[i + j];
#pragma unroll
        for (int j = 0; j < 8; ++j) ev[j] = a_src[sv[j] * NH + h];
#pragma unroll
        for (int j = 0; j < 8; ++j) wv[j] = *(const unsigned*)(h1 + (size_t)sv[j] * HC + 2 * lane);
#pragma unroll
        for (int j = 0; j < 8; ++j) {
            const float n = elog(ev[j] + ad);
            acc0 += n * blo(wv[j]);
            acc1 += n * bhi(wv[j]);
            den  += n;
        }
    }
    for (; i < end; ++i) {
        const int s = esrc_sorted[i];
        const float num = elog(a_src[s * NH + h] + ad);
        const unsigned w = *(const unsigned*)(h1 + (size_t)s * HC + 2 * lane);
        acc0 += num * blo(w);
        acc1 += num * bhi(w);
        den  += num;
    }
    const float inv = 1.f / (den + 1e-16f);

    // fused GEMM2: this wave holds the whole out1 row (2 channels / lane).
    const int k0 = 2 * lane;
    const float r0v = fmaxf(acc0 * inv + B1s[k0],     0.f);
    const float r1v = fmaxf(acc1 * inv + B1s[k0 + 1], 0.f);
    float p[NC];
#pragma unroll
    for (int c = 0; c < NC; ++c)
        p[c] = r0v * W2s[k0 * NC + c] + r1v * W2s[(k0 + 1) * NC + c];
    // 64-lane butterfly reduce (7 channels)
#pragma unroll
    for (int m = 1; m < 64; m <<= 1) {
#pragma unroll
        for (int c = 0; c < NC; ++c) p[c] += __shfl_xor(p[c], m);
    }
    if (lane == 0) {
        float ps = 0.f, pd = 0.f;
        float* hp = h2 + (size_t)node * NC;
#pragma unroll
        for (int c = 0; c < NC; ++c) {
            hp[c] = p[c];
            ps += p[c] * wc[OAS2 + c];
            pd += p[c] * wc[OAD2 + c];
        }
        a_src2[node] = ps;
        a_dst2[node] = pd;
    }
}

// ---------------- layer-2 fused gather ----------------
__global__ void gather2_kernel(
    const int* __restrict__ rowptr, const int* __restrict__ esrc_sorted,
    const float* __restrict__ a_src, const float* __restrict__ a_dst,
    const float* __restrict__ h2, const float* __restrict__ wc,
    void* __restrict__ out, const int* __restrict__ flags)
{
    const int node = blockIdx.x * 32 + (threadIdx.x >> 3);
    if (node >= NN) return;
    const int c = threadIdx.x & 7;
    const float ad = a_dst[node];
    const int start = rowptr[node];
    const int end   = rowptr[node + 1];
    const int cc = (c < NC) ? c : 0;
    float acc = 0.f, den = 0.f;
    int i = start;
    for (; i + 4 <= end; i += 4) {
        const int s0 = esrc_sorted[i + 0];
        const int s1 = esrc_sorted[i + 1];
        const int s2 = esrc_sorted[i + 2];
        const int s3 = esrc_sorted[i + 3];
        const float e0 = a_src[s0];
        const float e1 = a_src[s1];
        const float e2 = a_src[s2];
        const float e3 = a_src[s3];
        const float v0 = h2[s0 * NC + cc];
        const float v1 = h2[s1 * NC + cc];
        const float v2 = h2[s2 * NC + cc];
        const float v3 = h2[s3 * NC + cc];
        const float n0 = elog(e0 + ad);
        const float n1 = elog(e1 + ad);
        const float n2 = elog(e2 + ad);
        const float n3 = elog(e3 + ad);
        acc += n0 * v0 + n1 * v1 + n2 * v2 + n3 * v3;
        den += n0 + n1 + n2 + n3;
    }
    for (; i < end; ++i) {
        const int s = esrc_sorted[i];
        const float num = elog(a_src[s] + ad);
        den += num;
        acc += num * h2[s * NC + cc];
    }
    if (c >= NC) return;
    const float v = acc / (den + 1e-16f) + wc[OB2 + c];
    if (flags[0]) ((bf16*)out)[node * NC + c] = __float2bfloat16(v);
    else          ((float*)out)[node * NC + c] = v;
}

extern "C" void kernel_launch(void* const* d_in, const int* in_sizes, int n_in,
                              void* d_out, int out_size, void* d_ws, size_t ws_size,
                              hipStream_t stream)
{
    const void* x        = d_in[0];
    const void* eidx     = d_in[1];
    const void* W1       = d_in[2];
    const void* att_src1 = d_in[3];
    const void* att_dst1 = d_in[4];
    const void* b1       = d_in[5];
    const void* W2       = d_in[6];
    const void* att_src2 = d_in[7];
    const void* att_dst2 = d_in[8];
    const void* b2       = d_in[9];

    float* ws = (float*)d_ws;
    size_t o = 0;
    int*   flags  = (int*)(ws + o);            o += 16;
    float* wc     = ws + o;                    o += 65312;
    unsigned short* w1t = (unsigned short*)(ws + o); o += (HC * KPAD) / 2;
    int*   deg    = (int*)(ws + o);            o += 50000;
    int*   cur    = (int*)(ws + o);            o += 50000;   // contiguous with deg for one memset
    int*   rowptr = (int*)(ws + o);            o += 50016;
    int*   bsum   = (int*)(ws + o);            o += 256;
    int*   esrt   = (int*)(ws + o);            o += 850000;
    bf16*  h1     = (bf16*)(ws + o);           o += (size_t)NN * HC / 2;
    float* a_src1 = ws + o;                    o += (size_t)NN * NH;
    float* a_dst1 = ws + o;                    o += (size_t)NN * NH;
    float* h2     = ws + o;                    o += (size_t)NN * NC;
    float* a_src2 = ws + o;                    o += NN;
    float* a_dst2 = ws + o;                    o += NN;

    detect_kernel<<<1, 256, 0, stream>>>((const unsigned short*)x, (const unsigned int*)eidx,
                                         flags, rowptr);
    conv_all_kernel<<<(HC * KPAD + 255) / 256, 256, 0, stream>>>(
        W1, att_src1, att_dst1, b1, W2, att_src2, att_dst2, b2, wc, w1t, flags);
    hipMemsetAsync(deg, 0, 2 * (size_t)NN * sizeof(int), stream);
    hist_kernel<<<(ETOT + 255) / 256, 256, 0, stream>>>(eidx, deg, flags);
    scan_k1_kernel<<<(NN + 255) / 256, 256, 0, stream>>>(deg, bsum);
    scan_k2_kernel<<<1, 256, 0, stream>>>(bsum);
    scan_k3_kernel<<<(NN + 255) / 256, 256, 0, stream>>>(deg, bsum, rowptr);
    scatter_kernel<<<(ETOT + 255) / 256, 256, 0, stream>>>(eidx, rowptr, cur, esrt, flags);

    gemm1_mfma_kernel<<<(NN + GR1 - 1) / GR1, 256, 0, stream>>>(x, w1t, h1, flags);
    att1_kernel<<<(NN * NH + 255) / 256, 256, 0, stream>>>(h1, wc, a_src1, a_dst1);
    gather1_kernel<<<(NN + 3) / 4, 256, 0, stream>>>(rowptr, esrt, a_src1, a_dst1, h1, wc,
                                                     h2, a_src2, a_dst2);
    gather2_kernel<<<(NN + 31) / 32, 256, 0, stream>>>(rowptr, esrt, a_src2, a_dst2, h2, wc,
                                                       d_out, flags);
}